// Round 11
// baseline (205.376 us; speedup 1.0000x reference)
//
#include <hip/hip_runtime.h>
#include <hip/hip_bf16.h>

typedef __attribute__((ext_vector_type(8))) short short8;
typedef __attribute__((ext_vector_type(4))) short short4v;
typedef __attribute__((ext_vector_type(4))) float f32x4;

#define BB 2
#define LL 2048
#define DD 1024
#define HH 16
#define DHH 64
#define KK 1024
// 0.125 (1/sqrt(64)) * log2(e): softmax carried in exp2 domain
#define SCL 0.18033688011112042f
#define EXP2(x) __builtin_amdgcn_exp2f(x)

__device__ __forceinline__ void gload_lds16(const void* g, void* l) {
  __builtin_amdgcn_global_load_lds((const __attribute__((address_space(1))) void*)g,
                                   (__attribute__((address_space(3))) void*)l,
                                   16, 0, 0);
}

__device__ __forceinline__ f32x4 splat4(float x) {
  f32x4 v; v[0] = x; v[1] = x; v[2] = x; v[3] = x; return v;
}

__device__ __forceinline__ unsigned short f2b(float x) {
  __hip_bfloat16 h = __float2bfloat16(x);
  return *reinterpret_cast<unsigned short*>(&h);
}

// fused fp32 -> bf16 convert for x, w_in, w_out (one launch)
#define NX8  ((BB * LL * DD) / 8)      // 524288
#define NWI8 ((3 * DD * DD) / 8)       // 393216
#define NWO8 ((DD * DD) / 8)           // 131072
__global__ void cvt_all(const float* __restrict__ x,
                        const float* __restrict__ w_in,
                        const float* __restrict__ w_out,
                        __hip_bfloat16* __restrict__ xb,
                        __hip_bfloat16* __restrict__ w_inb,
                        __hip_bfloat16* __restrict__ w_outb) {
  int i = blockIdx.x * blockDim.x + threadIdx.x;
  const float* src;
  __hip_bfloat16* dst;
  int j;
  if (i < NX8)              { src = x;     dst = xb;     j = i; }
  else if (i < NX8 + NWI8)  { src = w_in;  dst = w_inb;  j = i - NX8; }
  else                      { src = w_out; dst = w_outb; j = i - NX8 - NWI8; }
  const f32x4 a = ((const f32x4*)src)[j * 2];
  const f32x4 b = ((const f32x4*)src)[j * 2 + 1];
  short8 o;
#pragma unroll
  for (int k = 0; k < 4; ++k) o[k] = (short)f2b(a[k]);
#pragma unroll
  for (int k = 0; k < 4; ++k) o[4 + k] = (short)f2b(b[k]);
  ((short8*)dst)[j] = o;
}

// C = A @ B^T (+bias). A: MxK bf16 row-major, B: NxK bf16 row-major. K=1024.
// QKV mode scatters into Q/K (B,H,L,DH) and V TRANSPOSED (B,H,DH,L), bf16.
// Direct mode writes fp32 C[m*N+n].
template<bool QKV>
__global__ void gemm_bt(const __hip_bfloat16* __restrict__ A,
                        const __hip_bfloat16* __restrict__ Bm,
                        const float* __restrict__ bias,
                        __hip_bfloat16* __restrict__ Cq,
                        __hip_bfloat16* __restrict__ Ck,
                        __hip_bfloat16* __restrict__ Cv,
                        float* __restrict__ Cd,
                        int N, int nbn) {
  __shared__ __align__(16) char As[8192];
  __shared__ __align__(16) char Bs[8192];
  const int tid = threadIdx.x;
  const int lane = tid & 63, wid = tid >> 6;
  const int l15 = lane & 15, lhi = lane >> 4;
  const int wm = wid >> 1, wn = wid & 1;
  const int bn = blockIdx.x % nbn, bm = blockIdx.x / nbn;
  const int m0 = bm * 128, n0 = bn * 128;

  f32x4 acc[4][4] = {};

  for (int kt = 0; kt < KK / 32; ++kt) {
    const int k0 = kt * 32;
    __syncthreads();
#pragma unroll
    for (int j = 0; j < 2; ++j) {
      int c = wid * 128 + j * 64 + lane;       // 16B chunk index
      int row = c >> 2;
      int ab = ((c & 3) * 16) ^ (((row >> 1) & 3) << 4);
      gload_lds16(A + (size_t)(m0 + row) * KK + k0 + (ab >> 1),
                  As + wid * 2048 + j * 1024);
    }
#pragma unroll
    for (int j = 0; j < 2; ++j) {
      int c = wid * 128 + j * 64 + lane;
      int row = c >> 2;
      int ab = ((c & 3) * 16) ^ (((row >> 1) & 3) << 4);
      gload_lds16(Bm + (size_t)(n0 + row) * KK + k0 + (ab >> 1),
                  Bs + wid * 2048 + j * 1024);
    }
    __syncthreads();

    short8 af[4], bf[4];
#pragma unroll
    for (int mf = 0; mf < 4; ++mf) {
      int row = wm * 64 + mf * 16 + l15;
      int byt = (lhi * 16) ^ (((row >> 1) & 3) << 4);
      af[mf] = *(const short8*)(As + row * 64 + byt);
    }
#pragma unroll
    for (int nf = 0; nf < 4; ++nf) {
      int row = wn * 64 + nf * 16 + l15;
      int byt = (lhi * 16) ^ (((row >> 1) & 3) << 4);
      bf[nf] = *(const short8*)(Bs + row * 64 + byt);
    }
#pragma unroll
    for (int mf = 0; mf < 4; ++mf)
#pragma unroll
      for (int nf = 0; nf < 4; ++nf)
        acc[mf][nf] = __builtin_amdgcn_mfma_f32_16x16x32_bf16(af[mf], bf[nf],
                                                              acc[mf][nf], 0, 0, 0);
  }

  // epilogue: C/D layout col=lane&15, row=(lane>>4)*4+reg
#pragma unroll
  for (int mf = 0; mf < 4; ++mf) {
#pragma unroll
    for (int nf = 0; nf < 4; ++nf) {
      const int n = n0 + wn * 64 + nf * 16 + l15;
      if constexpr (QKV) {
        const int sect = n >> 10;          // 0=q 1=k 2=v
        const int nn = n & 1023;
        const int h = nn >> 6, dh = nn & 63;
        const float bv = bias[n];
        const int m_base = m0 + wm * 64 + mf * 16 + lhi * 4;   // +r, same 2k page
        const int b = m_base >> 11, ml = m_base & 2047;
        if (sect == 2) {
          // V transposed: [b*H+h][dh][l]; 4 r-values are l-contiguous -> 8B store
          short4v v;
#pragma unroll
          for (int r = 0; r < 4; ++r) v[r] = (short)f2b(acc[mf][nf][r] + bv);
          *(short4v*)&Cv[(((size_t)(b * HH + h)) * DHH + dh) * LL + ml] = v;
        } else {
          __hip_bfloat16* dst = (sect == 0) ? Cq : Ck;
#pragma unroll
          for (int r = 0; r < 4; ++r)
            dst[(((size_t)(b * HH + h)) * LL + ml + r) * DHH + dh] =
                __float2bfloat16(acc[mf][nf][r] + bv);
        }
      } else {
#pragma unroll
        for (int r = 0; r < 4; ++r) {
          const int m = m0 + wm * 64 + mf * 16 + lhi * 4 + r;
          Cd[(size_t)m * N + n] = acc[mf][nf][r];
        }
      }
    }
  }
}

// Flash attention: 1024 blocks x 4 waves. Block owns strip pair (63-p, p):
// uniform 33 causal tiles. Per phase the 4 waves 4-way split the strip's
// kv-tiles; partials merged via LDS tree. Register discipline: K loaded in
// ks-halves (16 transient regs), V loaded late per-nf; no launch_bounds cap
// (r9/r10 spilled under the 128-reg cap).
__global__ void attn_fwd(
    const __hip_bfloat16* __restrict__ Q,
    const __hip_bfloat16* __restrict__ K,
    const __hip_bfloat16* __restrict__ VT,
    __hip_bfloat16* __restrict__ att,
    const int* __restrict__ maskp) {
  __shared__ __align__(16) char Pbuf[4][4096];  // per-wave P [row32][128B], swz
  __shared__ __align__(16) float Ob[2][32][68]; // merge partials (padded)
  __shared__ float Mb[2][32], Lb[2][32];
  const int tid = threadIdx.x;
  const int lane = tid & 63, wid = tid >> 6;
  const int l15 = lane & 15, lhi = lane >> 4;
  const int bid = blockIdx.x;
  const int pair = bid >> 5;                // 0..31
  const int bh = bid & 31;                  // head pinned to one XCD's L2
  const int causal = *maskp;
  const __hip_bfloat16* Qg = Q + (size_t)bh * LL * DHH;
  const __hip_bfloat16* Kg = K + (size_t)bh * LL * DHH;
  const __hip_bfloat16* VTg = VT + (size_t)bh * DHH * LL;
  char* Pw = Pbuf[wid];
  const int b_ = bh >> 4, h = bh & 15;

  for (int ph = 0; ph < 2; ++ph) {
    const int strip = ph ? pair : (63 - pair);
    const int r0 = strip * 32;

    // Q fragments (all 4 waves load the same strip)
    short8 aq[2][2];
#pragma unroll
    for (int mf = 0; mf < 2; ++mf)
#pragma unroll
      for (int ks = 0; ks < 2; ++ks)
        aq[mf][ks] = *(const short8*)(Qg + (size_t)(r0 + mf * 16 + l15) * DHH +
                                      ks * 32 + lhi * 8);

    f32x4 o[2][4] = {};
    f32x4 mrun[2], lrun[2];
    mrun[0] = splat4(-1e30f); mrun[1] = splat4(-1e30f);
    lrun[0] = splat4(0.0f);   lrun[1] = splat4(0.0f);

    const int nt = causal ? ((r0 + 31) >> 6) + 1 : (LL / 64);
    const int t0 = (wid * nt) >> 2;
    const int t1 = ((wid + 1) * nt) >> 2;

    for (int t = t0; t < t1; ++t) {
      const int kv0 = t * 64;
      f32x4 s[2][4] = {};

      // QK^T with K loaded in ks-halves: only 16 K-regs transiently live
#pragma unroll
      for (int ks = 0; ks < 2; ++ks) {
        short8 bkh[4];
#pragma unroll
        for (int nf = 0; nf < 4; ++nf)
          bkh[nf] = *(const short8*)(Kg + (size_t)(kv0 + nf * 16 + l15) * DHH +
                                     ks * 32 + lhi * 8);
        __builtin_amdgcn_s_setprio(1);
#pragma unroll
        for (int nf = 0; nf < 4; ++nf) {
          s[0][nf] = __builtin_amdgcn_mfma_f32_16x16x32_bf16(aq[0][ks], bkh[nf], s[0][nf], 0, 0, 0);
          s[1][nf] = __builtin_amdgcn_mfma_f32_16x16x32_bf16(aq[1][ks], bkh[nf], s[1][nf], 0, 0, 0);
        }
        __builtin_amdgcn_s_setprio(0);
      }

      const bool needmask = causal && (kv0 + 63 > r0);
      // per-mf: mask -> softmax -> P-store (frees s[mf] as it goes)
#pragma unroll
      for (int mf = 0; mf < 2; ++mf) {
#pragma unroll
        for (int nf = 0; nf < 4; ++nf) {
          const int kv = kv0 + nf * 16 + l15;
#pragma unroll
          for (int r = 0; r < 4; ++r) {
            float v = s[mf][nf][r] * SCL;
            if (needmask && kv > r0 + mf * 16 + lhi * 4 + r) v = -1e30f;
            s[mf][nf][r] = v;
          }
        }
        f32x4 pm = s[mf][0];
#pragma unroll
        for (int nf = 1; nf < 4; ++nf)
#pragma unroll
          for (int r = 0; r < 4; ++r) pm[r] = fmaxf(pm[r], s[mf][nf][r]);
#pragma unroll
        for (int d = 1; d < 16; d <<= 1)
#pragma unroll
          for (int r = 0; r < 4; ++r) pm[r] = fmaxf(pm[r], __shfl_xor(pm[r], d, 64));

        f32x4 rsum;
#pragma unroll
        for (int r = 0; r < 4; ++r) {
          const float mnew = fmaxf(mrun[mf][r], pm[r]);
          const float sc = EXP2(mrun[mf][r] - mnew);
          mrun[mf][r] = mnew;
          lrun[mf][r] *= sc;
          rsum[r] = 0.0f;
#pragma unroll
          for (int nf = 0; nf < 4; ++nf) o[mf][nf][r] *= sc;
        }
#pragma unroll
        for (int nf = 0; nf < 4; ++nf)
#pragma unroll
          for (int r = 0; r < 4; ++r) {
            float p = EXP2(s[mf][nf][r] - mrun[mf][r]);
            s[mf][nf][r] = p;
            rsum[r] += p;
          }
#pragma unroll
        for (int d = 1; d < 16; d <<= 1)
#pragma unroll
          for (int r = 0; r < 4; ++r) rsum[r] += __shfl_xor(rsum[r], d, 64);
#pragma unroll
        for (int r = 0; r < 4; ++r) lrun[mf][r] += rsum[r];

        // P -> wave-private LDS (swizzled)
#pragma unroll
        for (int nf = 0; nf < 4; ++nf)
#pragma unroll
          for (int r = 0; r < 4; ++r) {
            const int row = mf * 16 + lhi * 4 + r;
            const int cb = (nf * 16 + l15) * 2;
            *(__hip_bfloat16*)(Pw + row * 128 + (cb ^ ((row & 12) << 3))) =
                __float2bfloat16(s[mf][nf][r]);
          }
      }

      // PV: V^T loaded late per-nf (16 transient regs), P reloaded from LDS
#pragma unroll
      for (int nf = 0; nf < 4; ++nf) {
        short8 bv0 = *(const short8*)(VTg + (size_t)(nf * 16 + l15) * LL + kv0 + lhi * 8);
        short8 bv1 = *(const short8*)(VTg + (size_t)(nf * 16 + l15) * LL + kv0 + 32 + lhi * 8);
        __builtin_amdgcn_s_setprio(1);
#pragma unroll
        for (int mf = 0; mf < 2; ++mf) {
          const int row = mf * 16 + l15;
          short8 ap0 = *(const short8*)(Pw + row * 128 + ((lhi * 16) ^ ((row & 12) << 3)));
          short8 ap1 = *(const short8*)(Pw + row * 128 + ((64 + lhi * 16) ^ ((row & 12) << 3)));
          o[mf][nf] = __builtin_amdgcn_mfma_f32_16x16x32_bf16(ap0, bv0, o[mf][nf], 0, 0, 0);
          o[mf][nf] = __builtin_amdgcn_mfma_f32_16x16x32_bf16(ap1, bv1, o[mf][nf], 0, 0, 0);
        }
        __builtin_amdgcn_s_setprio(0);
      }
    }

    // ---- 4-way merge tree: w1->buf0, w3->buf1; w0+=buf0, w2+=buf1; w2->buf0; w0+=buf0
    auto dump = [&](int b) {
#pragma unroll
      for (int mf = 0; mf < 2; ++mf)
#pragma unroll
        for (int r = 0; r < 4; ++r) {
          const int row = mf * 16 + lhi * 4 + r;
          if (l15 == 0) { Mb[b][row] = mrun[mf][r]; Lb[b][row] = lrun[mf][r]; }
#pragma unroll
          for (int nf = 0; nf < 4; ++nf)
            Ob[b][row][nf * 16 + l15] = o[mf][nf][r];
        }
    };
    auto combine = [&](int b) {
#pragma unroll
      for (int mf = 0; mf < 2; ++mf)
#pragma unroll
        for (int r = 0; r < 4; ++r) {
          const int row = mf * 16 + lhi * 4 + r;
          const float mo = Mb[b][row], lo = Lb[b][row];
          const float mt = fmaxf(mrun[mf][r], mo);
          const float sr = EXP2(mrun[mf][r] - mt);
          const float so = EXP2(mo - mt);
          lrun[mf][r] = lrun[mf][r] * sr + lo * so;
          mrun[mf][r] = mt;
#pragma unroll
          for (int nf = 0; nf < 4; ++nf)
            o[mf][nf][r] = o[mf][nf][r] * sr + Ob[b][row][nf * 16 + l15] * so;
        }
    };

    __syncthreads();
    if (wid & 1) dump(wid >> 1);            // w1 -> buf0, w3 -> buf1
    __syncthreads();
    if (!(wid & 1)) combine(wid >> 1);      // w0 += buf0, w2 += buf1
    __syncthreads();
    if (wid == 2) dump(0);
    __syncthreads();
    if (wid == 0) {
      combine(0);
#pragma unroll
      for (int mf = 0; mf < 2; ++mf)
#pragma unroll
        for (int r = 0; r < 4; ++r) {
          const int row = mf * 16 + lhi * 4 + r;
          const float inv = 1.0f / lrun[mf][r];
          const int grow = r0 + row;
#pragma unroll
          for (int nf = 0; nf < 4; ++nf)
            att[((size_t)(b_ * LL + grow)) * DD + h * DHH + nf * 16 + l15] =
                __float2bfloat16(o[mf][nf][r] * inv);
        }
    }
    __syncthreads();                        // protect merge LDS for next phase
  }
}

extern "C" void kernel_launch(void* const* d_in, const int* in_sizes, int n_in,
                              void* d_out, int out_size, void* d_ws, size_t ws_size,
                              hipStream_t stream) {
  const float* x     = (const float*)d_in[0];
  const float* w_in  = (const float*)d_in[1];
  const float* b_in  = (const float*)d_in[2];
  const float* w_out = (const float*)d_in[3];
  const int* mask    = (const int*)d_in[4];
  float* out = (float*)d_out;

  char* ws = (char*)d_ws;
  const size_t MiB = 1024u * 1024u;
  __hip_bfloat16* xb    = (__hip_bfloat16*)(ws);             // 8 MiB
  __hip_bfloat16* w_inb = (__hip_bfloat16*)(ws + 8 * MiB);   // 6 MiB
  __hip_bfloat16* w_outb= (__hip_bfloat16*)(ws + 14 * MiB);  // 2 MiB
  __hip_bfloat16* Qb    = (__hip_bfloat16*)(ws + 16 * MiB);  // 8 MiB
  __hip_bfloat16* Kb    = (__hip_bfloat16*)(ws + 24 * MiB);  // 8 MiB
  __hip_bfloat16* Vtb   = (__hip_bfloat16*)(ws + 32 * MiB);  // 8 MiB (transposed)
  __hip_bfloat16* att   = (__hip_bfloat16*)(ws + 40 * MiB);  // 8 MiB

  // fused conversions: (524288+393216+131072)/256 = 4096 blocks
  cvt_all<<<dim3(4096), dim3(256), 0, stream>>>(x, w_in, w_out, xb, w_inb, w_outb);

  gemm_bt<true><<<dim3(32 * 24), dim3(256), 0, stream>>>(
      xb, w_inb, b_in, Qb, Kb, Vtb, nullptr, 3072, 24);
  attn_fwd<<<dim3(1024), dim3(256), 0, stream>>>(Qb, Kb, Vtb, att, mask);
  gemm_bt<false><<<dim3(32 * 8), dim3(256), 0, stream>>>(
      att, w_outb, nullptr, nullptr, nullptr, nullptr, out, 1024, 8);
}

// Round 12
// 160.686 us; speedup vs baseline: 1.2781x; 1.2781x over previous
//
#include <hip/hip_runtime.h>
#include <hip/hip_bf16.h>

typedef __attribute__((ext_vector_type(8))) short short8;
typedef __attribute__((ext_vector_type(4))) short short4v;
typedef __attribute__((ext_vector_type(4))) float f32x4;

#define BB 2
#define LL 2048
#define DD 1024
#define HH 16
#define DHH 64
#define KK 1024
// 0.125 (1/sqrt(64)) * log2(e): softmax carried in exp2 domain
#define SCL 0.18033688011112042f
#define EXP2(x) __builtin_amdgcn_exp2f(x)

__device__ __forceinline__ void gload_lds16(const void* g, void* l) {
  __builtin_amdgcn_global_load_lds((const __attribute__((address_space(1))) void*)g,
                                   (__attribute__((address_space(3))) void*)l,
                                   16, 0, 0);
}

__device__ __forceinline__ f32x4 splat4(float x) {
  f32x4 v; v[0] = x; v[1] = x; v[2] = x; v[3] = x; return v;
}

__device__ __forceinline__ unsigned short f2b(float x) {
  __hip_bfloat16 h = __float2bfloat16(x);
  return *reinterpret_cast<unsigned short*>(&h);
}

// fused fp32 -> bf16 convert for x, w_in, w_out (one launch)
#define NX8  ((BB * LL * DD) / 8)      // 524288
#define NWI8 ((3 * DD * DD) / 8)       // 393216
#define NWO8 ((DD * DD) / 8)           // 131072
__global__ void cvt_all(const float* __restrict__ x,
                        const float* __restrict__ w_in,
                        const float* __restrict__ w_out,
                        __hip_bfloat16* __restrict__ xb,
                        __hip_bfloat16* __restrict__ w_inb,
                        __hip_bfloat16* __restrict__ w_outb) {
  int i = blockIdx.x * blockDim.x + threadIdx.x;
  const float* src;
  __hip_bfloat16* dst;
  int j;
  if (i < NX8)              { src = x;     dst = xb;     j = i; }
  else if (i < NX8 + NWI8)  { src = w_in;  dst = w_inb;  j = i - NX8; }
  else                      { src = w_out; dst = w_outb; j = i - NX8 - NWI8; }
  const f32x4 a = ((const f32x4*)src)[j * 2];
  const f32x4 b = ((const f32x4*)src)[j * 2 + 1];
  short8 o;
#pragma unroll
  for (int k = 0; k < 4; ++k) o[k] = (short)f2b(a[k]);
#pragma unroll
  for (int k = 0; k < 4; ++k) o[4 + k] = (short)f2b(b[k]);
  ((short8*)dst)[j] = o;
}

// C = A @ B^T (+bias). A: MxK bf16 row-major, B: NxK bf16 row-major. K=1024.
// QKV mode scatters into Q/K (B,H,L,DH) and V TRANSPOSED (B,H,DH,L), bf16.
// Direct mode writes fp32 C[m*N+n].
template<bool QKV>
__global__ void gemm_bt(const __hip_bfloat16* __restrict__ A,
                        const __hip_bfloat16* __restrict__ Bm,
                        const float* __restrict__ bias,
                        __hip_bfloat16* __restrict__ Cq,
                        __hip_bfloat16* __restrict__ Ck,
                        __hip_bfloat16* __restrict__ Cv,
                        float* __restrict__ Cd,
                        int N, int nbn) {
  __shared__ __align__(16) char As[8192];
  __shared__ __align__(16) char Bs[8192];
  const int tid = threadIdx.x;
  const int lane = tid & 63, wid = tid >> 6;
  const int l15 = lane & 15, lhi = lane >> 4;
  const int wm = wid >> 1, wn = wid & 1;
  const int bn = blockIdx.x % nbn, bm = blockIdx.x / nbn;
  const int m0 = bm * 128, n0 = bn * 128;

  f32x4 acc[4][4] = {};

  for (int kt = 0; kt < KK / 32; ++kt) {
    const int k0 = kt * 32;
    __syncthreads();
#pragma unroll
    for (int j = 0; j < 2; ++j) {
      int c = wid * 128 + j * 64 + lane;       // 16B chunk index
      int row = c >> 2;
      int ab = ((c & 3) * 16) ^ (((row >> 1) & 3) << 4);
      gload_lds16(A + (size_t)(m0 + row) * KK + k0 + (ab >> 1),
                  As + wid * 2048 + j * 1024);
    }
#pragma unroll
    for (int j = 0; j < 2; ++j) {
      int c = wid * 128 + j * 64 + lane;
      int row = c >> 2;
      int ab = ((c & 3) * 16) ^ (((row >> 1) & 3) << 4);
      gload_lds16(Bm + (size_t)(n0 + row) * KK + k0 + (ab >> 1),
                  Bs + wid * 2048 + j * 1024);
    }
    __syncthreads();

    short8 af[4], bf[4];
#pragma unroll
    for (int mf = 0; mf < 4; ++mf) {
      int row = wm * 64 + mf * 16 + l15;
      int byt = (lhi * 16) ^ (((row >> 1) & 3) << 4);
      af[mf] = *(const short8*)(As + row * 64 + byt);
    }
#pragma unroll
    for (int nf = 0; nf < 4; ++nf) {
      int row = wn * 64 + nf * 16 + l15;
      int byt = (lhi * 16) ^ (((row >> 1) & 3) << 4);
      bf[nf] = *(const short8*)(Bs + row * 64 + byt);
    }
#pragma unroll
    for (int mf = 0; mf < 4; ++mf)
#pragma unroll
      for (int nf = 0; nf < 4; ++nf)
        acc[mf][nf] = __builtin_amdgcn_mfma_f32_16x16x32_bf16(af[mf], bf[nf],
                                                              acc[mf][nf], 0, 0, 0);
  }

  // epilogue: C/D layout col=lane&15, row=(lane>>4)*4+reg
#pragma unroll
  for (int mf = 0; mf < 4; ++mf) {
#pragma unroll
    for (int nf = 0; nf < 4; ++nf) {
      const int n = n0 + wn * 64 + nf * 16 + l15;
      if constexpr (QKV) {
        const int sect = n >> 10;          // 0=q 1=k 2=v
        const int nn = n & 1023;
        const int h = nn >> 6, dh = nn & 63;
        const float bv = bias[n];
        const int m_base = m0 + wm * 64 + mf * 16 + lhi * 4;   // +r, same 2k page
        const int b = m_base >> 11, ml = m_base & 2047;
        if (sect == 2) {
          // V transposed: [b*H+h][dh][l]; 4 r-values are l-contiguous -> 8B store
          short4v v;
#pragma unroll
          for (int r = 0; r < 4; ++r) v[r] = (short)f2b(acc[mf][nf][r] + bv);
          *(short4v*)&Cv[(((size_t)(b * HH + h)) * DHH + dh) * LL + ml] = v;
        } else {
          __hip_bfloat16* dst = (sect == 0) ? Cq : Ck;
#pragma unroll
          for (int r = 0; r < 4; ++r)
            dst[(((size_t)(b * HH + h)) * LL + ml + r) * DHH + dh] =
                __float2bfloat16(acc[mf][nf][r] + bv);
        }
      } else {
#pragma unroll
        for (int r = 0; r < 4; ++r) {
          const int m = m0 + wm * 64 + mf * 16 + lhi * 4 + r;
          Cd[(size_t)m * N + n] = acc[mf][nf][r];
        }
      }
    }
  }
}

// Flash attention: 1024 blocks x 4 waves. Block owns strip pair (63-p, p):
// uniform 33 causal tiles; per phase the 4 waves 4-way split the kv-tiles,
// partials merged via LDS tree. amdgpu_waves_per_eu(1,4) pins the allocator's
// occupancy TARGET to 4 waves/EU -> 128-VGPR budget (the default heuristic
// targeted 8 -> 64 regs -> 400MB scratch spill in r9-r11).
__global__ __launch_bounds__(256)
__attribute__((amdgpu_waves_per_eu(1, 4)))
void attn_fwd(
    const __hip_bfloat16* __restrict__ Q,
    const __hip_bfloat16* __restrict__ K,
    const __hip_bfloat16* __restrict__ VT,
    __hip_bfloat16* __restrict__ att,
    const int* __restrict__ maskp) {
  __shared__ __align__(16) char Pbuf[4][4096];  // per-wave P [row32][128B], swz
  __shared__ __align__(16) float Ob[2][32][68]; // merge partials (padded)
  __shared__ float Mb[2][32], Lb[2][32];
  const int tid = threadIdx.x;
  const int lane = tid & 63, wid = tid >> 6;
  const int l15 = lane & 15, lhi = lane >> 4;
  const int bid = blockIdx.x;
  const int pair = bid >> 5;                // 0..31
  const int bh = bid & 31;                  // head pinned to one XCD's L2
  const int causal = *maskp;
  const __hip_bfloat16* Qg = Q + (size_t)bh * LL * DHH;
  const __hip_bfloat16* Kg = K + (size_t)bh * LL * DHH;
  const __hip_bfloat16* VTg = VT + (size_t)bh * DHH * LL;
  char* Pw = Pbuf[wid];
  const int b_ = bh >> 4, h = bh & 15;

  for (int ph = 0; ph < 2; ++ph) {
    const int strip = ph ? pair : (63 - pair);
    const int r0 = strip * 32;

    // Q fragments (all 4 waves load the same strip)
    short8 aq[2][2];
#pragma unroll
    for (int mf = 0; mf < 2; ++mf)
#pragma unroll
      for (int ks = 0; ks < 2; ++ks)
        aq[mf][ks] = *(const short8*)(Qg + (size_t)(r0 + mf * 16 + l15) * DHH +
                                      ks * 32 + lhi * 8);

    f32x4 o[2][4] = {};
    f32x4 mrun[2], lrun[2];
    mrun[0] = splat4(-1e30f); mrun[1] = splat4(-1e30f);
    lrun[0] = splat4(0.0f);   lrun[1] = splat4(0.0f);

    const int nt = causal ? ((r0 + 31) >> 6) + 1 : (LL / 64);
    const int t0 = (wid * nt) >> 2;
    const int t1 = ((wid + 1) * nt) >> 2;

    for (int t = t0; t < t1; ++t) {
      const int kv0 = t * 64;
      f32x4 s[2][4] = {};

      // QK^T with K loaded in ks-halves: only 16 K-regs transiently live
#pragma unroll
      for (int ks = 0; ks < 2; ++ks) {
        short8 bkh[4];
#pragma unroll
        for (int nf = 0; nf < 4; ++nf)
          bkh[nf] = *(const short8*)(Kg + (size_t)(kv0 + nf * 16 + l15) * DHH +
                                     ks * 32 + lhi * 8);
        __builtin_amdgcn_s_setprio(1);
#pragma unroll
        for (int nf = 0; nf < 4; ++nf) {
          s[0][nf] = __builtin_amdgcn_mfma_f32_16x16x32_bf16(aq[0][ks], bkh[nf], s[0][nf], 0, 0, 0);
          s[1][nf] = __builtin_amdgcn_mfma_f32_16x16x32_bf16(aq[1][ks], bkh[nf], s[1][nf], 0, 0, 0);
        }
        __builtin_amdgcn_s_setprio(0);
      }

      const bool needmask = causal && (kv0 + 63 > r0);
      // per-mf: mask -> softmax -> P-store (frees s[mf] as it goes)
#pragma unroll
      for (int mf = 0; mf < 2; ++mf) {
#pragma unroll
        for (int nf = 0; nf < 4; ++nf) {
          const int kv = kv0 + nf * 16 + l15;
#pragma unroll
          for (int r = 0; r < 4; ++r) {
            float v = s[mf][nf][r] * SCL;
            if (needmask && kv > r0 + mf * 16 + lhi * 4 + r) v = -1e30f;
            s[mf][nf][r] = v;
          }
        }
        f32x4 pm = s[mf][0];
#pragma unroll
        for (int nf = 1; nf < 4; ++nf)
#pragma unroll
          for (int r = 0; r < 4; ++r) pm[r] = fmaxf(pm[r], s[mf][nf][r]);
#pragma unroll
        for (int d = 1; d < 16; d <<= 1)
#pragma unroll
          for (int r = 0; r < 4; ++r) pm[r] = fmaxf(pm[r], __shfl_xor(pm[r], d, 64));

        f32x4 rsum;
#pragma unroll
        for (int r = 0; r < 4; ++r) {
          const float mnew = fmaxf(mrun[mf][r], pm[r]);
          const float sc = EXP2(mrun[mf][r] - mnew);
          mrun[mf][r] = mnew;
          lrun[mf][r] *= sc;
          rsum[r] = 0.0f;
#pragma unroll
          for (int nf = 0; nf < 4; ++nf) o[mf][nf][r] *= sc;
        }
#pragma unroll
        for (int nf = 0; nf < 4; ++nf)
#pragma unroll
          for (int r = 0; r < 4; ++r) {
            float p = EXP2(s[mf][nf][r] - mrun[mf][r]);
            s[mf][nf][r] = p;
            rsum[r] += p;
          }
#pragma unroll
        for (int d = 1; d < 16; d <<= 1)
#pragma unroll
          for (int r = 0; r < 4; ++r) rsum[r] += __shfl_xor(rsum[r], d, 64);
#pragma unroll
        for (int r = 0; r < 4; ++r) lrun[mf][r] += rsum[r];

        // P -> wave-private LDS (swizzled)
#pragma unroll
        for (int nf = 0; nf < 4; ++nf)
#pragma unroll
          for (int r = 0; r < 4; ++r) {
            const int row = mf * 16 + lhi * 4 + r;
            const int cb = (nf * 16 + l15) * 2;
            *(__hip_bfloat16*)(Pw + row * 128 + (cb ^ ((row & 12) << 3))) =
                __float2bfloat16(s[mf][nf][r]);
          }
      }

      // PV: V^T loaded late per-nf (16 transient regs), P reloaded from LDS
#pragma unroll
      for (int nf = 0; nf < 4; ++nf) {
        short8 bv0 = *(const short8*)(VTg + (size_t)(nf * 16 + l15) * LL + kv0 + lhi * 8);
        short8 bv1 = *(const short8*)(VTg + (size_t)(nf * 16 + l15) * LL + kv0 + 32 + lhi * 8);
        __builtin_amdgcn_s_setprio(1);
#pragma unroll
        for (int mf = 0; mf < 2; ++mf) {
          const int row = mf * 16 + l15;
          short8 ap0 = *(const short8*)(Pw + row * 128 + ((lhi * 16) ^ ((row & 12) << 3)));
          short8 ap1 = *(const short8*)(Pw + row * 128 + ((64 + lhi * 16) ^ ((row & 12) << 3)));
          o[mf][nf] = __builtin_amdgcn_mfma_f32_16x16x32_bf16(ap0, bv0, o[mf][nf], 0, 0, 0);
          o[mf][nf] = __builtin_amdgcn_mfma_f32_16x16x32_bf16(ap1, bv1, o[mf][nf], 0, 0, 0);
        }
        __builtin_amdgcn_s_setprio(0);
      }
    }

    // ---- 4-way merge tree: w1->buf0, w3->buf1; w0+=buf0, w2+=buf1; w2->buf0; w0+=buf0
    auto dump = [&](int b) {
#pragma unroll
      for (int mf = 0; mf < 2; ++mf)
#pragma unroll
        for (int r = 0; r < 4; ++r) {
          const int row = mf * 16 + lhi * 4 + r;
          if (l15 == 0) { Mb[b][row] = mrun[mf][r]; Lb[b][row] = lrun[mf][r]; }
#pragma unroll
          for (int nf = 0; nf < 4; ++nf)
            Ob[b][row][nf * 16 + l15] = o[mf][nf][r];
        }
    };
    auto combine = [&](int b) {
#pragma unroll
      for (int mf = 0; mf < 2; ++mf)
#pragma unroll
        for (int r = 0; r < 4; ++r) {
          const int row = mf * 16 + lhi * 4 + r;
          const float mo = Mb[b][row], lo = Lb[b][row];
          const float mt = fmaxf(mrun[mf][r], mo);
          const float sr = EXP2(mrun[mf][r] - mt);
          const float so = EXP2(mo - mt);
          lrun[mf][r] = lrun[mf][r] * sr + lo * so;
          mrun[mf][r] = mt;
#pragma unroll
          for (int nf = 0; nf < 4; ++nf)
            o[mf][nf][r] = o[mf][nf][r] * sr + Ob[b][row][nf * 16 + l15] * so;
        }
    };

    __syncthreads();
    if (wid & 1) dump(wid >> 1);            // w1 -> buf0, w3 -> buf1
    __syncthreads();
    if (!(wid & 1)) combine(wid >> 1);      // w0 += buf0, w2 += buf1
    __syncthreads();
    if (wid == 2) dump(0);
    __syncthreads();
    if (wid == 0) {
      combine(0);
#pragma unroll
      for (int mf = 0; mf < 2; ++mf)
#pragma unroll
        for (int r = 0; r < 4; ++r) {
          const int row = mf * 16 + lhi * 4 + r;
          const float inv = 1.0f / lrun[mf][r];
          const int grow = r0 + row;
#pragma unroll
          for (int nf = 0; nf < 4; ++nf)
            att[((size_t)(b_ * LL + grow)) * DD + h * DHH + nf * 16 + l15] =
                __float2bfloat16(o[mf][nf][r] * inv);
        }
    }
    __syncthreads();                        // protect merge LDS for next phase
  }
}

extern "C" void kernel_launch(void* const* d_in, const int* in_sizes, int n_in,
                              void* d_out, int out_size, void* d_ws, size_t ws_size,
                              hipStream_t stream) {
  const float* x     = (const float*)d_in[0];
  const float* w_in  = (const float*)d_in[1];
  const float* b_in  = (const float*)d_in[2];
  const float* w_out = (const float*)d_in[3];
  const int* mask    = (const int*)d_in[4];
  float* out = (float*)d_out;

  char* ws = (char*)d_ws;
  const size_t MiB = 1024u * 1024u;
  __hip_bfloat16* xb    = (__hip_bfloat16*)(ws);             // 8 MiB
  __hip_bfloat16* w_inb = (__hip_bfloat16*)(ws + 8 * MiB);   // 6 MiB
  __hip_bfloat16* w_outb= (__hip_bfloat16*)(ws + 14 * MiB);  // 2 MiB
  __hip_bfloat16* Qb    = (__hip_bfloat16*)(ws + 16 * MiB);  // 8 MiB
  __hip_bfloat16* Kb    = (__hip_bfloat16*)(ws + 24 * MiB);  // 8 MiB
  __hip_bfloat16* Vtb   = (__hip_bfloat16*)(ws + 32 * MiB);  // 8 MiB (transposed)
  __hip_bfloat16* att   = (__hip_bfloat16*)(ws + 40 * MiB);  // 8 MiB

  // fused conversions: (524288+393216+131072)/256 = 4096 blocks
  cvt_all<<<dim3(4096), dim3(256), 0, stream>>>(x, w_in, w_out, xb, w_inb, w_outb);

  gemm_bt<true><<<dim3(32 * 24), dim3(256), 0, stream>>>(
      xb, w_inb, b_in, Qb, Kb, Vtb, nullptr, 3072, 24);
  attn_fwd<<<dim3(1024), dim3(256), 0, stream>>>(Qb, Kb, Vtb, att, mask);
  gemm_bt<false><<<dim3(32 * 8), dim3(256), 0, stream>>>(
      att, w_outb, nullptr, nullptr, nullptr, nullptr, out, 1024, 8);
}

// Round 13
// 158.973 us; speedup vs baseline: 1.2919x; 1.0108x over previous
//
#include <hip/hip_runtime.h>
#include <hip/hip_bf16.h>

typedef __attribute__((ext_vector_type(8))) short short8;
typedef __attribute__((ext_vector_type(4))) short short4v;
typedef __attribute__((ext_vector_type(4))) float f32x4;

#define BB 2
#define LL 2048
#define DD 1024
#define HH 16
#define DHH 64
#define KK 1024
// 0.125 (1/sqrt(64)) * log2(e): softmax carried in exp2 domain
#define SCL 0.18033688011112042f
#define EXP2(x) __builtin_amdgcn_exp2f(x)

__device__ __forceinline__ void gload_lds16(const void* g, void* l) {
  __builtin_amdgcn_global_load_lds((const __attribute__((address_space(1))) void*)g,
                                   (__attribute__((address_space(3))) void*)l,
                                   16, 0, 0);
}

__device__ __forceinline__ f32x4 splat4(float x) {
  f32x4 v; v[0] = x; v[1] = x; v[2] = x; v[3] = x; return v;
}

__device__ __forceinline__ unsigned short f2b(float x) {
  __hip_bfloat16 h = __float2bfloat16(x);
  return *reinterpret_cast<unsigned short*>(&h);
}

// fused fp32 -> bf16 convert for x, w_in, w_out (one launch)
#define NX8  ((BB * LL * DD) / 8)      // 524288
#define NWI8 ((3 * DD * DD) / 8)       // 393216
#define NWO8 ((DD * DD) / 8)           // 131072
__global__ void cvt_all(const float* __restrict__ x,
                        const float* __restrict__ w_in,
                        const float* __restrict__ w_out,
                        __hip_bfloat16* __restrict__ xb,
                        __hip_bfloat16* __restrict__ w_inb,
                        __hip_bfloat16* __restrict__ w_outb) {
  int i = blockIdx.x * blockDim.x + threadIdx.x;
  const float* src;
  __hip_bfloat16* dst;
  int j;
  if (i < NX8)              { src = x;     dst = xb;     j = i; }
  else if (i < NX8 + NWI8)  { src = w_in;  dst = w_inb;  j = i - NX8; }
  else                      { src = w_out; dst = w_outb; j = i - NX8 - NWI8; }
  const f32x4 a = ((const f32x4*)src)[j * 2];
  const f32x4 b = ((const f32x4*)src)[j * 2 + 1];
  short8 o;
#pragma unroll
  for (int k = 0; k < 4; ++k) o[k] = (short)f2b(a[k]);
#pragma unroll
  for (int k = 0; k < 4; ++k) o[4 + k] = (short)f2b(b[k]);
  ((short8*)dst)[j] = o;
}

// C = A @ B^T (+bias). A: MxK bf16 row-major, B: NxK bf16 row-major. K=1024.
// QKV mode scatters into Q/K (B,H,L,DH) and V TRANSPOSED (B,H,DH,L), bf16.
// Direct mode writes fp32 C[m*N+n].
template<bool QKV>
__global__ void gemm_bt(const __hip_bfloat16* __restrict__ A,
                        const __hip_bfloat16* __restrict__ Bm,
                        const float* __restrict__ bias,
                        __hip_bfloat16* __restrict__ Cq,
                        __hip_bfloat16* __restrict__ Ck,
                        __hip_bfloat16* __restrict__ Cv,
                        float* __restrict__ Cd,
                        int N, int nbn) {
  __shared__ __align__(16) char As[8192];
  __shared__ __align__(16) char Bs[8192];
  const int tid = threadIdx.x;
  const int lane = tid & 63, wid = tid >> 6;
  const int l15 = lane & 15, lhi = lane >> 4;
  const int wm = wid >> 1, wn = wid & 1;
  const int bn = blockIdx.x % nbn, bm = blockIdx.x / nbn;
  const int m0 = bm * 128, n0 = bn * 128;

  f32x4 acc[4][4] = {};

  for (int kt = 0; kt < KK / 32; ++kt) {
    const int k0 = kt * 32;
    __syncthreads();
#pragma unroll
    for (int j = 0; j < 2; ++j) {
      int c = wid * 128 + j * 64 + lane;       // 16B chunk index
      int row = c >> 2;
      int ab = ((c & 3) * 16) ^ (((row >> 1) & 3) << 4);
      gload_lds16(A + (size_t)(m0 + row) * KK + k0 + (ab >> 1),
                  As + wid * 2048 + j * 1024);
    }
#pragma unroll
    for (int j = 0; j < 2; ++j) {
      int c = wid * 128 + j * 64 + lane;
      int row = c >> 2;
      int ab = ((c & 3) * 16) ^ (((row >> 1) & 3) << 4);
      gload_lds16(Bm + (size_t)(n0 + row) * KK + k0 + (ab >> 1),
                  Bs + wid * 2048 + j * 1024);
    }
    __syncthreads();

    short8 af[4], bf[4];
#pragma unroll
    for (int mf = 0; mf < 4; ++mf) {
      int row = wm * 64 + mf * 16 + l15;
      int byt = (lhi * 16) ^ (((row >> 1) & 3) << 4);
      af[mf] = *(const short8*)(As + row * 64 + byt);
    }
#pragma unroll
    for (int nf = 0; nf < 4; ++nf) {
      int row = wn * 64 + nf * 16 + l15;
      int byt = (lhi * 16) ^ (((row >> 1) & 3) << 4);
      bf[nf] = *(const short8*)(Bs + row * 64 + byt);
    }
#pragma unroll
    for (int mf = 0; mf < 4; ++mf)
#pragma unroll
      for (int nf = 0; nf < 4; ++nf)
        acc[mf][nf] = __builtin_amdgcn_mfma_f32_16x16x32_bf16(af[mf], bf[nf],
                                                              acc[mf][nf], 0, 0, 0);
  }

  // epilogue: C/D layout col=lane&15, row=(lane>>4)*4+reg
#pragma unroll
  for (int mf = 0; mf < 4; ++mf) {
#pragma unroll
    for (int nf = 0; nf < 4; ++nf) {
      const int n = n0 + wn * 64 + nf * 16 + l15;
      if constexpr (QKV) {
        const int sect = n >> 10;          // 0=q 1=k 2=v
        const int nn = n & 1023;
        const int h = nn >> 6, dh = nn & 63;
        const float bv = bias[n];
        const int m_base = m0 + wm * 64 + mf * 16 + lhi * 4;   // +r, same 2k page
        const int b = m_base >> 11, ml = m_base & 2047;
        if (sect == 2) {
          // V transposed: [b*H+h][dh][l]; 4 r-values are l-contiguous -> 8B store
          short4v v;
#pragma unroll
          for (int r = 0; r < 4; ++r) v[r] = (short)f2b(acc[mf][nf][r] + bv);
          *(short4v*)&Cv[(((size_t)(b * HH + h)) * DHH + dh) * LL + ml] = v;
        } else {
          __hip_bfloat16* dst = (sect == 0) ? Cq : Ck;
#pragma unroll
          for (int r = 0; r < 4; ++r)
            dst[(((size_t)(b * HH + h)) * LL + ml + r) * DHH + dh] =
                __float2bfloat16(acc[mf][nf][r] + bv);
        }
      } else {
#pragma unroll
        for (int r = 0; r < 4; ++r) {
          const int m = m0 + wm * 64 + mf * 16 + lhi * 4 + r;
          Cd[(size_t)m * N + n] = acc[mf][nf][r];
        }
      }
    }
  }
}

// Flash attention: 1024 blocks x 4 waves. Block owns strip pair (63-p, p):
// uniform 33 causal tiles; per phase the 4 waves 4-way split the kv-tiles,
// partials merged via LDS tree. waves_per_eu(1,3) -> 170-VGPR budget: the
// full-ILP body (V preloaded under softmax, peak ~152 live) fits w/o spill;
// r12's 128-budget slimming dribbled loads and exposed 4+ waits/tile.
__global__ __launch_bounds__(256)
__attribute__((amdgpu_waves_per_eu(1, 3)))
void attn_fwd(
    const __hip_bfloat16* __restrict__ Q,
    const __hip_bfloat16* __restrict__ K,
    const __hip_bfloat16* __restrict__ VT,
    __hip_bfloat16* __restrict__ att,
    const int* __restrict__ maskp) {
  __shared__ __align__(16) char Pbuf[4][4096];  // per-wave P [row32][128B], swz
  __shared__ __align__(16) float Ob[2][32][68]; // merge partials (padded)
  __shared__ float Mb[2][32], Lb[2][32];
  const int tid = threadIdx.x;
  const int lane = tid & 63, wid = tid >> 6;
  const int l15 = lane & 15, lhi = lane >> 4;
  const int bid = blockIdx.x;
  const int pair = bid >> 5;                // 0..31
  const int bh = bid & 31;                  // head pinned to one XCD's L2
  const int causal = *maskp;
  const __hip_bfloat16* Qg = Q + (size_t)bh * LL * DHH;
  const __hip_bfloat16* Kg = K + (size_t)bh * LL * DHH;
  const __hip_bfloat16* VTg = VT + (size_t)bh * DHH * LL;
  char* Pw = Pbuf[wid];
  const int b_ = bh >> 4, h = bh & 15;

  for (int ph = 0; ph < 2; ++ph) {
    const int strip = ph ? pair : (63 - pair);
    const int r0 = strip * 32;

    // Q fragments (all 4 waves load the same strip)
    short8 aq[2][2];
#pragma unroll
    for (int mf = 0; mf < 2; ++mf)
#pragma unroll
      for (int ks = 0; ks < 2; ++ks)
        aq[mf][ks] = *(const short8*)(Qg + (size_t)(r0 + mf * 16 + l15) * DHH +
                                      ks * 32 + lhi * 8);

    f32x4 o[2][4] = {};
    f32x4 mrun[2], lrun[2];
    mrun[0] = splat4(-1e30f); mrun[1] = splat4(-1e30f);
    lrun[0] = splat4(0.0f);   lrun[1] = splat4(0.0f);

    const int nt = causal ? ((r0 + 31) >> 6) + 1 : (LL / 64);
    const int t0 = (wid * nt) >> 2;
    const int t1 = ((wid + 1) * nt) >> 2;

    for (int t = t0; t < t1; ++t) {
      const int kv0 = t * 64;
      f32x4 s[2][4] = {};

      // K half 0 loads first (oldest in vmcnt queue), then ALL V loads:
      // QK^T waits only for K; V stays in flight under softmax.
      short8 bkh[4];
#pragma unroll
      for (int nf = 0; nf < 4; ++nf)
        bkh[nf] = *(const short8*)(Kg + (size_t)(kv0 + nf * 16 + l15) * DHH +
                                   lhi * 8);
      short8 bv[4][2];
#pragma unroll
      for (int nf = 0; nf < 4; ++nf)
#pragma unroll
        for (int ks = 0; ks < 2; ++ks)
          bv[nf][ks] = *(const short8*)(VTg + (size_t)(nf * 16 + l15) * LL +
                                        kv0 + ks * 32 + lhi * 8);

      __builtin_amdgcn_s_setprio(1);
#pragma unroll
      for (int nf = 0; nf < 4; ++nf) {
        s[0][nf] = __builtin_amdgcn_mfma_f32_16x16x32_bf16(aq[0][0], bkh[nf], s[0][nf], 0, 0, 0);
        s[1][nf] = __builtin_amdgcn_mfma_f32_16x16x32_bf16(aq[1][0], bkh[nf], s[1][nf], 0, 0, 0);
      }
      __builtin_amdgcn_s_setprio(0);
      // K half 1
#pragma unroll
      for (int nf = 0; nf < 4; ++nf)
        bkh[nf] = *(const short8*)(Kg + (size_t)(kv0 + nf * 16 + l15) * DHH +
                                   32 + lhi * 8);
      __builtin_amdgcn_s_setprio(1);
#pragma unroll
      for (int nf = 0; nf < 4; ++nf) {
        s[0][nf] = __builtin_amdgcn_mfma_f32_16x16x32_bf16(aq[0][1], bkh[nf], s[0][nf], 0, 0, 0);
        s[1][nf] = __builtin_amdgcn_mfma_f32_16x16x32_bf16(aq[1][1], bkh[nf], s[1][nf], 0, 0, 0);
      }
      __builtin_amdgcn_s_setprio(0);

      const bool needmask = causal && (kv0 + 63 > r0);
      // per-mf: mask -> softmax -> P-store (V loads in flight underneath)
#pragma unroll
      for (int mf = 0; mf < 2; ++mf) {
#pragma unroll
        for (int nf = 0; nf < 4; ++nf) {
          const int kv = kv0 + nf * 16 + l15;
#pragma unroll
          for (int r = 0; r < 4; ++r) {
            float v = s[mf][nf][r] * SCL;
            if (needmask && kv > r0 + mf * 16 + lhi * 4 + r) v = -1e30f;
            s[mf][nf][r] = v;
          }
        }
        f32x4 pm = s[mf][0];
#pragma unroll
        for (int nf = 1; nf < 4; ++nf)
#pragma unroll
          for (int r = 0; r < 4; ++r) pm[r] = fmaxf(pm[r], s[mf][nf][r]);
#pragma unroll
        for (int d = 1; d < 16; d <<= 1)
#pragma unroll
          for (int r = 0; r < 4; ++r) pm[r] = fmaxf(pm[r], __shfl_xor(pm[r], d, 64));

        f32x4 rsum;
#pragma unroll
        for (int r = 0; r < 4; ++r) {
          const float mnew = fmaxf(mrun[mf][r], pm[r]);
          const float sc = EXP2(mrun[mf][r] - mnew);
          mrun[mf][r] = mnew;
          lrun[mf][r] *= sc;
          rsum[r] = 0.0f;
#pragma unroll
          for (int nf = 0; nf < 4; ++nf) o[mf][nf][r] *= sc;
        }
#pragma unroll
        for (int nf = 0; nf < 4; ++nf)
#pragma unroll
          for (int r = 0; r < 4; ++r) {
            float p = EXP2(s[mf][nf][r] - mrun[mf][r]);
            s[mf][nf][r] = p;
            rsum[r] += p;
          }
#pragma unroll
        for (int d = 1; d < 16; d <<= 1)
#pragma unroll
          for (int r = 0; r < 4; ++r) rsum[r] += __shfl_xor(rsum[r], d, 64);
#pragma unroll
        for (int r = 0; r < 4; ++r) lrun[mf][r] += rsum[r];

        // P -> wave-private LDS (swizzled)
#pragma unroll
        for (int nf = 0; nf < 4; ++nf)
#pragma unroll
          for (int r = 0; r < 4; ++r) {
            const int row = mf * 16 + lhi * 4 + r;
            const int cb = (nf * 16 + l15) * 2;
            *(__hip_bfloat16*)(Pw + row * 128 + (cb ^ ((row & 12) << 3))) =
                __float2bfloat16(s[mf][nf][r]);
          }
      }

      // PV: V already resident in regs, P reloaded from LDS
      __builtin_amdgcn_s_setprio(1);
#pragma unroll
      for (int mf = 0; mf < 2; ++mf) {
        const int row = mf * 16 + l15;
        short8 ap0 = *(const short8*)(Pw + row * 128 + ((lhi * 16) ^ ((row & 12) << 3)));
        short8 ap1 = *(const short8*)(Pw + row * 128 + ((64 + lhi * 16) ^ ((row & 12) << 3)));
#pragma unroll
        for (int nf = 0; nf < 4; ++nf) {
          o[mf][nf] = __builtin_amdgcn_mfma_f32_16x16x32_bf16(ap0, bv[nf][0], o[mf][nf], 0, 0, 0);
          o[mf][nf] = __builtin_amdgcn_mfma_f32_16x16x32_bf16(ap1, bv[nf][1], o[mf][nf], 0, 0, 0);
        }
      }
      __builtin_amdgcn_s_setprio(0);
    }

    // ---- 4-way merge tree: w1->buf0, w3->buf1; w0+=buf0, w2+=buf1; w2->buf0; w0+=buf0
    auto dump = [&](int b) {
#pragma unroll
      for (int mf = 0; mf < 2; ++mf)
#pragma unroll
        for (int r = 0; r < 4; ++r) {
          const int row = mf * 16 + lhi * 4 + r;
          if (l15 == 0) { Mb[b][row] = mrun[mf][r]; Lb[b][row] = lrun[mf][r]; }
#pragma unroll
          for (int nf = 0; nf < 4; ++nf)
            Ob[b][row][nf * 16 + l15] = o[mf][nf][r];
        }
    };
    auto combine = [&](int b) {
#pragma unroll
      for (int mf = 0; mf < 2; ++mf)
#pragma unroll
        for (int r = 0; r < 4; ++r) {
          const int row = mf * 16 + lhi * 4 + r;
          const float mo = Mb[b][row], lo = Lb[b][row];
          const float mt = fmaxf(mrun[mf][r], mo);
          const float sr = EXP2(mrun[mf][r] - mt);
          const float so = EXP2(mo - mt);
          lrun[mf][r] = lrun[mf][r] * sr + lo * so;
          mrun[mf][r] = mt;
#pragma unroll
          for (int nf = 0; nf < 4; ++nf)
            o[mf][nf][r] = o[mf][nf][r] * sr + Ob[b][row][nf * 16 + l15] * so;
        }
    };

    __syncthreads();
    if (wid & 1) dump(wid >> 1);            // w1 -> buf0, w3 -> buf1
    __syncthreads();
    if (!(wid & 1)) combine(wid >> 1);      // w0 += buf0, w2 += buf1
    __syncthreads();
    if (wid == 2) dump(0);
    __syncthreads();
    if (wid == 0) {
      combine(0);
#pragma unroll
      for (int mf = 0; mf < 2; ++mf)
#pragma unroll
        for (int r = 0; r < 4; ++r) {
          const int row = mf * 16 + lhi * 4 + r;
          const float inv = 1.0f / lrun[mf][r];
          const int grow = r0 + row;
#pragma unroll
          for (int nf = 0; nf < 4; ++nf)
            att[((size_t)(b_ * LL + grow)) * DD + h * DHH + nf * 16 + l15] =
                __float2bfloat16(o[mf][nf][r] * inv);
        }
    }
    __syncthreads();                        // protect merge LDS for next phase
  }
}

extern "C" void kernel_launch(void* const* d_in, const int* in_sizes, int n_in,
                              void* d_out, int out_size, void* d_ws, size_t ws_size,
                              hipStream_t stream) {
  const float* x     = (const float*)d_in[0];
  const float* w_in  = (const float*)d_in[1];
  const float* b_in  = (const float*)d_in[2];
  const float* w_out = (const float*)d_in[3];
  const int* mask    = (const int*)d_in[4];
  float* out = (float*)d_out;

  char* ws = (char*)d_ws;
  const size_t MiB = 1024u * 1024u;
  __hip_bfloat16* xb    = (__hip_bfloat16*)(ws);             // 8 MiB
  __hip_bfloat16* w_inb = (__hip_bfloat16*)(ws + 8 * MiB);   // 6 MiB
  __hip_bfloat16* w_outb= (__hip_bfloat16*)(ws + 14 * MiB);  // 2 MiB
  __hip_bfloat16* Qb    = (__hip_bfloat16*)(ws + 16 * MiB);  // 8 MiB
  __hip_bfloat16* Kb    = (__hip_bfloat16*)(ws + 24 * MiB);  // 8 MiB
  __hip_bfloat16* Vtb   = (__hip_bfloat16*)(ws + 32 * MiB);  // 8 MiB (transposed)
  __hip_bfloat16* att   = (__hip_bfloat16*)(ws + 40 * MiB);  // 8 MiB

  // fused conversions: (524288+393216+131072)/256 = 4096 blocks
  cvt_all<<<dim3(4096), dim3(256), 0, stream>>>(x, w_in, w_out, xb, w_inb, w_outb);

  gemm_bt<true><<<dim3(32 * 24), dim3(256), 0, stream>>>(
      xb, w_inb, b_in, Qb, Kb, Vtb, nullptr, 3072, 24);
  attn_fwd<<<dim3(1024), dim3(256), 0, stream>>>(Qb, Kb, Vtb, att, mask);
  gemm_bt<false><<<dim3(32 * 8), dim3(256), 0, stream>>>(
      att, w_outb, nullptr, nullptr, nullptr, nullptr, out, 1024, 8);
}